// Round 1
// baseline (47518.539 us; speedup 1.0000x reference)
//
#include <hip/hip_runtime.h>
#include <math.h>

// ---- problem constants ----
constexpr int B_   = 64;
constexpr int S_   = 197;
constexpr int D_   = 768;
constexpr int H_   = 12;
constexpr int DH_  = 64;
constexpr int FF_  = 3072;
constexpr int DEPTH_ = 12;
constexpr int NP_  = 196;
constexpr int M_   = B_ * S_;    // 12608 rows (divisible by 64: 197*64)
constexpr int MP_  = B_ * NP_;   // 12544 rows (divisible by 64: 196*64)

// ================= block reduce (256 threads = 4 waves) =================
__device__ __forceinline__ float block_reduce_sum(float val) {
    __shared__ float sm[4];
    #pragma unroll
    for (int off = 32; off > 0; off >>= 1) val += __shfl_xor(val, off, 64);
    int wid = threadIdx.x >> 6;
    if ((threadIdx.x & 63) == 0) sm[wid] = val;
    __syncthreads();
    float r = (sm[0] + sm[1]) + (sm[2] + sm[3]);
    __syncthreads();   // allow re-use of sm on next call
    return r;
}

// ================= generic fp32 tiled GEMM =================
// C[M,N] = act(A[M,K] @ B + bias[N]) (+ res[M,N] if RES)
// TRANSB=false: B is [K,N] row-major.  TRANSB=true: B is [N,K] row-major.
// ACT: 0 = none, 1 = exact GELU.
#define BM 64
#define BN 64
#define BK 16
#define LDP 68   // padded leading dim (keeps 16B alignment, kills bank conflicts)

template<bool TRANSB, int ACT, bool RES>
__global__ __launch_bounds__(256)
void gemm_k(const float* __restrict__ A, const float* __restrict__ Bm,
            const float* __restrict__ bias, const float* __restrict__ res,
            float* __restrict__ C, int M, int N, int K) {
    __shared__ float As[BK][LDP];
    __shared__ float Bs[BK][LDP];
    const int tid = threadIdx.x;
    const int m0 = blockIdx.y * BM;
    const int n0 = blockIdx.x * BN;
    const int tx = tid & 15;   // output col group
    const int ty = tid >> 4;   // output row group
    float acc[4][4] = {};

    for (int k0 = 0; k0 < K; k0 += BK) {
        // A tile: As[kk][r] = A[m0+r, k0+kk]
        {
            const int c = tid & 15;
            int r = tid >> 4;
            #pragma unroll
            for (int t = 0; t < 4; ++t, r += 16)
                As[c][r] = A[(size_t)(m0 + r) * K + (k0 + c)];
        }
        if (!TRANSB) {
            const int c = tid & 63;
            int r = tid >> 6;
            #pragma unroll
            for (int t = 0; t < 4; ++t, r += 4)
                Bs[r][c] = Bm[(size_t)(k0 + r) * N + (n0 + c)];
        } else {
            const int kk = tid & 15;
            int c = tid >> 4;
            #pragma unroll
            for (int t = 0; t < 4; ++t, c += 16)
                Bs[kk][c] = Bm[(size_t)(n0 + c) * K + (k0 + kk)];
        }
        __syncthreads();
        #pragma unroll
        for (int kk = 0; kk < BK; ++kk) {
            float a[4], b[4];
            #pragma unroll
            for (int i = 0; i < 4; ++i) a[i] = As[kk][ty * 4 + i];
            #pragma unroll
            for (int j = 0; j < 4; ++j) b[j] = Bs[kk][tx * 4 + j];
            #pragma unroll
            for (int i = 0; i < 4; ++i)
                #pragma unroll
                for (int j = 0; j < 4; ++j)
                    acc[i][j] += a[i] * b[j];
        }
        __syncthreads();
    }

    #pragma unroll
    for (int i = 0; i < 4; ++i) {
        const int m = m0 + ty * 4 + i;
        #pragma unroll
        for (int j = 0; j < 4; ++j) {
            const int n = n0 + tx * 4 + j;
            float v = acc[i][j] + bias[n];
            if (ACT == 1) v = 0.5f * v * (1.0f + erff(v * 0.70710678118654752f));
            if (RES) v += res[(size_t)m * N + n];
            C[(size_t)m * N + n] = v;
        }
    }
}

// ================= im2col for 16x16 stride-16 patches =================
// pm[b*196+p, c*256+ky*16+kx] = x[b, c, py*16+ky, px*16+kx]
__global__ void im2col_k(const float* __restrict__ x, float* __restrict__ pm) {
    size_t idx = (size_t)blockIdx.x * 256 + threadIdx.x;
    if (idx >= (size_t)MP_ * 768) return;
    int col = (int)(idx % 768);
    int row = (int)(idx / 768);
    int b = row / NP_, p = row % NP_;
    int c = col >> 8, rem = col & 255, ky = rem >> 4, kx = rem & 15;
    int py = p / 14, px = p % 14;
    pm[idx] = x[(((size_t)b * 3 + c) * 224 + (py * 16 + ky)) * 224 + (px * 16 + kx)];
}

// ================= assemble h = concat(cls, patch_embed) + pos =================
__global__ void assemble_k(const float* __restrict__ pe, const float* __restrict__ cls,
                           const float* __restrict__ pos, float* __restrict__ h) {
    size_t idx = (size_t)blockIdx.x * 256 + threadIdx.x;
    if (idx >= (size_t)M_ * D_) return;
    int d = (int)(idx % D_);
    int row = (int)(idx / D_);
    int b = row / S_, s = row % S_;
    float v;
    if (s == 0) v = cls[d] + pos[d];
    else        v = pe[((size_t)b * NP_ + (s - 1)) * D_ + d] + pos[(size_t)s * D_ + d];
    h[idx] = v;
}

// ================= LayerNorm (width 768, 256 threads/row) =================
__global__ __launch_bounds__(256)
void ln_k(const float* __restrict__ x, size_t xstride,
          float* __restrict__ y, size_t ystride,
          const float* __restrict__ s, const float* __restrict__ b) {
    const float* xr = x + (size_t)blockIdx.x * xstride;
    float* yr = y + (size_t)blockIdx.x * ystride;
    const int tid = threadIdx.x;
    float v[3];
    float sum = 0.f;
    #pragma unroll
    for (int t = 0; t < 3; ++t) { v[t] = xr[tid + t * 256]; sum += v[t]; }
    sum = block_reduce_sum(sum);
    const float mu = sum * (1.0f / 768.0f);
    float vs = 0.f;
    #pragma unroll
    for (int t = 0; t < 3; ++t) { float d = v[t] - mu; vs += d * d; }
    vs = block_reduce_sum(vs);
    const float rstd = rsqrtf(vs * (1.0f / 768.0f) + 1e-6f);
    #pragma unroll
    for (int t = 0; t < 3; ++t) {
        int c = tid + t * 256;
        yr[c] = (v[t] - mu) * rstd * s[c] + b[c];
    }
}

// ================= attention: one wave per (b, h, s) row =================
__global__ __launch_bounds__(64)
void attn_k(const float* __restrict__ q, const float* __restrict__ k,
            const float* __restrict__ v, float* __restrict__ o) {
    __shared__ float qs[64];
    __shared__ float sc[S_];
    const int s = blockIdx.x, h = blockIdx.y, b = blockIdx.z;
    const int tid = threadIdx.x;
    const size_t rowbase = ((size_t)b * S_ + s) * D_ + h * DH_;
    const size_t kb = (size_t)b * S_ * D_ + h * DH_;

    qs[tid] = q[rowbase + tid] * 0.125f;   // scale = 64^-0.5
    __syncthreads();

    for (int j = tid; j < S_; j += 64) {
        const float* kr = k + kb + (size_t)j * D_;
        float dot = 0.f;
        #pragma unroll
        for (int dh = 0; dh < 64; ++dh) dot += qs[dh] * kr[dh];
        sc[j] = dot;
    }
    __syncthreads();

    float mx = -1e30f;
    for (int j = tid; j < S_; j += 64) mx = fmaxf(mx, sc[j]);
    #pragma unroll
    for (int off = 32; off > 0; off >>= 1) mx = fmaxf(mx, __shfl_xor(mx, off, 64));

    float lsum = 0.f;
    for (int j = tid; j < S_; j += 64) {
        float e = expf(sc[j] - mx);
        sc[j] = e;
        lsum += e;
    }
    #pragma unroll
    for (int off = 32; off > 0; off >>= 1) lsum += __shfl_xor(lsum, off, 64);
    __syncthreads();

    float acc = 0.f;
    for (int j = 0; j < S_; ++j) acc += sc[j] * v[kb + (size_t)j * D_ + tid];
    o[rowbase + tid] = acc / lsum;
}

// ================= launch =================
extern "C" void kernel_launch(void* const* d_in, const int* in_sizes, int n_in,
                              void* d_out, int out_size, void* d_ws, size_t ws_size,
                              hipStream_t stream) {
    const float* x       = (const float*)d_in[0];
    const float* patch_w = (const float*)d_in[1];
    const float* patch_b = (const float*)d_in[2];
    const float* cls_tok = (const float*)d_in[3];
    const float* pos_emb = (const float*)d_in[4];
    const float* ln1_s   = (const float*)d_in[5];
    const float* ln1_b   = (const float*)d_in[6];
    const float* qw      = (const float*)d_in[7];
    const float* qb      = (const float*)d_in[8];
    const float* kw      = (const float*)d_in[9];
    const float* kb      = (const float*)d_in[10];
    const float* vw      = (const float*)d_in[11];
    const float* vb      = (const float*)d_in[12];
    const float* pw      = (const float*)d_in[13];
    const float* pb      = (const float*)d_in[14];
    const float* ln2_s   = (const float*)d_in[15];
    const float* ln2_b   = (const float*)d_in[16];
    const float* fc1_w   = (const float*)d_in[17];
    const float* fc1_b   = (const float*)d_in[18];
    const float* fc2_w   = (const float*)d_in[19];
    const float* fc2_b   = (const float*)d_in[20];
    const float* lnf_s   = (const float*)d_in[21];
    const float* lnf_b   = (const float*)d_in[22];
    float* out = (float*)d_out;

    // workspace layout (floats)
    float* ws = (float*)d_ws;
    const size_t MD = (size_t)M_ * D_;
    float* h = ws;
    float* y = h + MD;
    float* q = y + MD;
    float* k = q + MD;
    float* v = k + MD;
    float* u = v + MD;             // M_*FF_ floats; also reused as im2col buffer

    const dim3 blk256(256);
    const dim3 gD(D_ / BN, M_ / BM);       // (12, 197)
    const dim3 gFF(FF_ / BN, M_ / BM);     // (48, 197)
    const dim3 gP(D_ / BN, MP_ / BM);      // (12, 196)

    // ---- patch embed ----
    {
        size_t n = (size_t)MP_ * 768;
        im2col_k<<<dim3((n + 255) / 256), blk256, 0, stream>>>(x, u);
        // q <- patches @ patch_w^T + patch_b
        gemm_k<true, 0, false><<<gP, blk256, 0, stream>>>(u, patch_w, patch_b, nullptr, q, MP_, D_, 768);
        size_t n2 = (size_t)M_ * D_;
        assemble_k<<<dim3((n2 + 255) / 256), blk256, 0, stream>>>(q, cls_tok, pos_emb, h);
    }

    // ---- transformer blocks ----
    for (int l = 0; l < DEPTH_; ++l) {
        const size_t oDD = (size_t)l * D_ * D_;
        const size_t oD  = (size_t)l * D_;
        const size_t oDF = (size_t)l * D_ * FF_;
        const size_t oF  = (size_t)l * FF_;

        ln_k<<<dim3(M_), blk256, 0, stream>>>(h, D_, y, D_, ln1_s + oD, ln1_b + oD);
        gemm_k<false, 0, false><<<gD, blk256, 0, stream>>>(y, qw + oDD, qb + oD, nullptr, q, M_, D_, D_);
        gemm_k<false, 0, false><<<gD, blk256, 0, stream>>>(y, kw + oDD, kb + oD, nullptr, k, M_, D_, D_);
        gemm_k<false, 0, false><<<gD, blk256, 0, stream>>>(y, vw + oDD, vb + oD, nullptr, v, M_, D_, D_);
        attn_k<<<dim3(S_, H_, B_), dim3(64), 0, stream>>>(q, k, v, y);   // o -> y
        gemm_k<false, 0, true><<<gD, blk256, 0, stream>>>(y, pw + oDD, pb + oD, h, h, M_, D_, D_);
        ln_k<<<dim3(M_), blk256, 0, stream>>>(h, D_, y, D_, ln2_s + oD, ln2_b + oD);
        gemm_k<false, 1, false><<<gFF, blk256, 0, stream>>>(y, fc1_w + oDF, fc1_b + oF, nullptr, u, M_, FF_, D_);
        gemm_k<false, 0, true><<<gD, blk256, 0, stream>>>(u, fc2_w + oDF, fc2_b + oD, h, h, M_, D_, FF_);
    }

    // ---- final LN on CLS rows only ----
    ln_k<<<dim3(B_), blk256, 0, stream>>>(h, (size_t)S_ * D_, out, D_, lnf_s, lnf_b);
}

// Round 2
// 5728.756 us; speedup vs baseline: 8.2947x; 8.2947x over previous
//
#include <hip/hip_runtime.h>
#include <math.h>

// ---- problem constants ----
constexpr int B_   = 64;
constexpr int S_   = 197;
constexpr int D_   = 768;
constexpr int H_   = 12;
constexpr int FF_  = 3072;
constexpr int DEPTH_ = 12;
constexpr int NP_  = 196;
constexpr int M_   = B_ * S_;    // 12608
constexpr int MP_  = B_ * NP_;   // 12544 (= 98*128)
constexpr int MPAD = 12672;      // 99*128

typedef __attribute__((ext_vector_type(8))) short  bf16x8;
typedef __attribute__((ext_vector_type(4))) float  f32x4;
typedef unsigned short ushort_t;

__device__ __forceinline__ ushort_t f2bf(float x) {
    unsigned u = __builtin_bit_cast(unsigned, x);
    unsigned r = u + 0x7FFFu + ((u >> 16) & 1u);
    return (ushort_t)(r >> 16);
}

#define GLOAD_LDS16(g, l)                                                      \
    __builtin_amdgcn_global_load_lds(                                          \
        (const __attribute__((address_space(1))) void*)(g),                    \
        (__attribute__((address_space(3))) void*)(l), 16, 0, 0)

// ====================== MFMA GEMM (m97 structure) ======================
// C[M,N] = epi(A[M,K] @ Bt[N,K]^T + bias)   A,Bt bf16; acc f32.
// EPI: 0 = bf16 out, 1 = bf16 out + GELU, 2 = f32 out + residual, 3 = f32 out.
constexpr int BM = 128, BN = 128, BK = 64;

template<int EPI>
__global__ __launch_bounds__(256)
void mm_k(const ushort_t* __restrict__ A, const ushort_t* __restrict__ Bt,
          const float* __restrict__ bias, const float* __restrict__ res,
          void* __restrict__ Cout, int M, int N, int K) {
    __shared__ __align__(16) ushort_t As[BM * BK];
    __shared__ __align__(16) ushort_t Bs[BN * BK];
    const int tid  = threadIdx.x;
    const int wid  = tid >> 6;
    const int lane = tid & 63;
    const int m0 = blockIdx.y * BM;
    const int n0 = blockIdx.x * BN;
    const int wr = wid >> 1, wc = wid & 1;

    const int srow = lane >> 3;          // 0..7
    const int scol = (lane & 7) * 8;     // element col within BK

    f32x4 acc[4][4];
    #pragma unroll
    for (int m = 0; m < 4; ++m)
        #pragma unroll
        for (int n = 0; n < 4; ++n)
            acc[m][n] = (f32x4){0.f, 0.f, 0.f, 0.f};

    for (int k0 = 0; k0 < K; k0 += BK) {
        #pragma unroll
        for (int i = 0; i < 4; ++i) {
            const int c = wid * 4 + i;          // chunk 0..15 (8 rows each)
            GLOAD_LDS16(A  + (size_t)(m0 + c * 8 + srow) * K + k0 + scol, &As[c * 512]);
            GLOAD_LDS16(Bt + (size_t)(n0 + c * 8 + srow) * K + k0 + scol, &Bs[c * 512]);
        }
        __syncthreads();
        #pragma unroll
        for (int kk = 0; kk < 2; ++kk) {
            bf16x8 av[4], bv[4];
            #pragma unroll
            for (int m = 0; m < 4; ++m)
                av[m] = *(const bf16x8*)&As[(wr * 64 + m * 16 + (lane & 15)) * 64 + kk * 32 + (lane >> 4) * 8];
            #pragma unroll
            for (int n = 0; n < 4; ++n)
                bv[n] = *(const bf16x8*)&Bs[(wc * 64 + n * 16 + (lane & 15)) * 64 + kk * 32 + (lane >> 4) * 8];
            #pragma unroll
            for (int m = 0; m < 4; ++m)
                #pragma unroll
                for (int n = 0; n < 4; ++n)
                    acc[m][n] = __builtin_amdgcn_mfma_f32_16x16x32_bf16(av[m], bv[n], acc[m][n], 0, 0, 0);
        }
        __syncthreads();
    }

    const int cr = wr * 64 + (lane >> 4) * 4;
    const int cc = wc * 64 + (lane & 15);
    #pragma unroll
    for (int n = 0; n < 4; ++n) {
        const int col = n0 + cc + n * 16;
        const float bcol = bias[col];
        #pragma unroll
        for (int m = 0; m < 4; ++m) {
            #pragma unroll
            for (int j = 0; j < 4; ++j) {
                const int row = m0 + cr + m * 16 + j;
                float v = acc[m][n][j] + bcol;
                if (EPI == 1) v = 0.5f * v * (1.0f + erff(v * 0.70710678118654752f));
                if (EPI == 2) v += res[(size_t)row * N + col];
                if (EPI <= 1) ((ushort_t*)Cout)[(size_t)row * N + col] = f2bf(v);
                else          ((float*)Cout)[(size_t)row * N + col] = v;
            }
        }
    }
}

// ====================== MFMA attention ======================
// One block per (h, b). qkv: [MPAD rows][2304] bf16 (q|k|v each 768).
// Writes O (bf16) into o[row][768] slice cols [h*64, h*64+64).
constexpr int SKV = 224;     // padded KV length (7 k-tiles of 32)
constexpr int VLD = 232;     // padded Vt row length (elements)

__global__ __launch_bounds__(256)
void attn2_k(const ushort_t* __restrict__ qkv, ushort_t* __restrict__ o) {
    __shared__ __align__(16) ushort_t Ks[SKV * 64];   // [j][dh], XOR-swizzled
    __shared__ __align__(16) ushort_t Vt[64 * VLD];   // [dh][j]
    __shared__ __align__(16) ushort_t Pw[4 * 512];    // per-wave 16x32, swizzled
    const int h = blockIdx.x, b = blockIdx.y;
    const int tid = threadIdx.x, wid = tid >> 6, lane = tid & 63;
    const size_t baseq = (size_t)(b * S_) * 2304 + h * 64;

    // ---- stage K (swizzled) and V^T ----
    {
        const int jr  = tid >> 3;          // 0..31
        const int dh0 = (tid & 7) * 8;
        for (int pass = 0; pass < 7; ++pass) {
            const int j = pass * 32 + jr;
            bf16x8 kv = {0, 0, 0, 0, 0, 0, 0, 0};
            bf16x8 vv = {0, 0, 0, 0, 0, 0, 0, 0};
            if (j < S_) {
                kv = *(const bf16x8*)&qkv[baseq + (size_t)j * 2304 + 768  + dh0];
                vv = *(const bf16x8*)&qkv[baseq + (size_t)j * 2304 + 1536 + dh0];
            }
            const int koff = (j * 128 + dh0 * 2) ^ ((j & 7) << 4);
            *(bf16x8*)((char*)Ks + koff) = kv;
            #pragma unroll
            for (int i = 0; i < 8; ++i) Vt[(dh0 + i) * VLD + j] = (ushort_t)vv[i];
        }
    }
    __syncthreads();

    char* const pwb = (char*)Pw + wid * 1024;

    for (int it = 0; it < 4; ++it) {
        // ---- Q fragments (A-operand: row = lane&15) ----
        int sq = it * 64 + wid * 16 + (lane & 15);
        const int sqc = (sq < S_) ? sq : (S_ - 1);
        bf16x8 qf[2];
        #pragma unroll
        for (int kk = 0; kk < 2; ++kk)
            qf[kk] = *(const bf16x8*)&qkv[baseq + (size_t)sqc * 2304 + kk * 32 + (lane >> 4) * 8];

        // ---- S = Q K^T ----
        f32x4 sa[14];
        #pragma unroll
        for (int nf = 0; nf < 14; ++nf) sa[nf] = (f32x4){0.f, 0.f, 0.f, 0.f};
        #pragma unroll
        for (int kk = 0; kk < 2; ++kk) {
            #pragma unroll
            for (int nf = 0; nf < 14; ++nf) {
                const int j = nf * 16 + (lane & 15);
                const int off = (j * 128 + kk * 64 + (lane >> 4) * 16) ^ ((j & 7) << 4);
                bf16x8 kf = *(const bf16x8*)((const char*)Ks + off);
                sa[nf] = __builtin_amdgcn_mfma_f32_16x16x32_bf16(qf[kk], kf, sa[nf], 0, 0, 0);
            }
        }

        // ---- softmax (rows = (lane>>4)*4 + r, cols = lane&15 + 16*nf) ----
        const int jcol = lane & 15;
        float mx[4] = {-1e30f, -1e30f, -1e30f, -1e30f};
        #pragma unroll
        for (int nf = 0; nf < 14; ++nf)
            #pragma unroll
            for (int r = 0; r < 4; ++r) mx[r] = fmaxf(mx[r], sa[nf][r]);
        float ls[4];
        #pragma unroll
        for (int r = 0; r < 4; ++r) {
            float m = mx[r] * 0.125f;
            m = fmaxf(m, __shfl_xor(m, 1, 64));
            m = fmaxf(m, __shfl_xor(m, 2, 64));
            m = fmaxf(m, __shfl_xor(m, 4, 64));
            m = fmaxf(m, __shfl_xor(m, 8, 64));
            float s = 0.f;
            #pragma unroll
            for (int nf = 0; nf < 14; ++nf) {
                const int j = nf * 16 + jcol;
                float p = (j < S_) ? exp2f((sa[nf][r] * 0.125f - m) * 1.44269504088896f) : 0.f;
                sa[nf][r] = p;
                s += p;
            }
            s += __shfl_xor(s, 1, 64);
            s += __shfl_xor(s, 2, 64);
            s += __shfl_xor(s, 4, 64);
            s += __shfl_xor(s, 8, 64);
            ls[r] = s;
        }

        // ---- O = P V (per 32-col chunk: transpose P via per-wave LDS) ----
        f32x4 oa[4];
        #pragma unroll
        for (int nf = 0; nf < 4; ++nf) oa[nf] = (f32x4){0.f, 0.f, 0.f, 0.f};
        #pragma unroll
        for (int kt = 0; kt < 7; ++kt) {
            #pragma unroll
            for (int half = 0; half < 2; ++half) {
                #pragma unroll
                for (int r = 0; r < 4; ++r) {
                    const int qr = (lane >> 4) * 4 + r;
                    const int jl = half * 16 + jcol;
                    const int off = (qr * 64 + jl * 2) ^ (((qr >> 1) & 3) << 4);
                    *(ushort_t*)(pwb + off) = f2bf(sa[kt * 2 + half][r]);
                }
            }
            const int arow = lane & 15;
            const int aoff = (arow * 64 + (lane >> 4) * 16) ^ (((arow >> 1) & 3) << 4);
            bf16x8 pa = *(const bf16x8*)(pwb + aoff);
            #pragma unroll
            for (int nf = 0; nf < 4; ++nf) {
                const int dh = nf * 16 + (lane & 15);
                bf16x8 vb = *(const bf16x8*)((const char*)Vt + dh * (VLD * 2) + (kt * 32 + (lane >> 4) * 8) * 2);
                oa[nf] = __builtin_amdgcn_mfma_f32_16x16x32_bf16(pa, vb, oa[nf], 0, 0, 0);
            }
        }

        // ---- store ----
        #pragma unroll
        for (int r = 0; r < 4; ++r) {
            const int so = it * 64 + wid * 16 + (lane >> 4) * 4 + r;
            if (so < S_) {
                const float inv = 1.0f / ls[r];
                #pragma unroll
                for (int nf = 0; nf < 4; ++nf)
                    o[(size_t)(b * S_ + so) * 768 + h * 64 + nf * 16 + (lane & 15)] = f2bf(oa[nf][r] * inv);
            }
        }
    }
}

// ====================== small kernels ======================
// transpose + cast: out[l][c][r] (bf16) = in[l][r][c] (f32)
__global__ __launch_bounds__(256)
void tcast_k(const float* __restrict__ in, ushort_t* __restrict__ out,
             int R, int C, size_t in_ls, size_t out_ls) {
    __shared__ float t[32][33];
    const float* ip = in + (size_t)blockIdx.z * in_ls;
    ushort_t* op = out + (size_t)blockIdx.z * out_ls;
    const int c0 = blockIdx.x * 32, r0 = blockIdx.y * 32;
    const int tx = threadIdx.x & 31, ty = threadIdx.x >> 5;
    #pragma unroll
    for (int i = 0; i < 4; ++i)
        t[ty + i * 8][tx] = ip[(size_t)(r0 + ty + i * 8) * C + c0 + tx];
    __syncthreads();
    #pragma unroll
    for (int i = 0; i < 4; ++i)
        op[(size_t)(c0 + ty + i * 8) * R + r0 + tx] = f2bf(t[tx][ty + i * 8]);
}

__global__ void cast_k(const float* __restrict__ in, ushort_t* __restrict__ out, int n) {
    int i = blockIdx.x * 256 + threadIdx.x;
    if (i < n) out[i] = f2bf(in[i]);
}

__global__ void biascat_k(const float* __restrict__ qb, const float* __restrict__ kb,
                          const float* __restrict__ vb, float* __restrict__ out) {
    int i = blockIdx.x * 256 + threadIdx.x;       // l*2304 + n
    if (i >= DEPTH_ * 2304) return;
    int l = i / 2304, n = i % 2304;
    float v = (n < 768) ? qb[l * 768 + n] : (n < 1536) ? kb[l * 768 + n - 768] : vb[l * 768 + n - 1536];
    out[i] = v;
}

__global__ void zeroyb_k(ushort_t* __restrict__ yb) {
    int i = blockIdx.x * 256 + threadIdx.x;       // 64 pad rows x 768
    if (i < (MPAD - M_) * 768) yb[(size_t)M_ * 768 + i] = 0;
}

__global__ void im2col_k(const float* __restrict__ x, ushort_t* __restrict__ pm) {
    size_t idx = (size_t)blockIdx.x * 256 + threadIdx.x;
    if (idx >= (size_t)MP_ * 768) return;
    int col = (int)(idx % 768);
    int row = (int)(idx / 768);
    int b = row / NP_, p = row % NP_;
    int c = col >> 8, rem = col & 255, ky = rem >> 4, kx = rem & 15;
    int py = p / 14, px = p % 14;
    pm[idx] = f2bf(x[(((size_t)b * 3 + c) * 224 + (py * 16 + ky)) * 224 + (px * 16 + kx)]);
}

__global__ void assemble_k(const float* __restrict__ pe, const float* __restrict__ cls,
                           const float* __restrict__ pos, float* __restrict__ h) {
    size_t idx = (size_t)blockIdx.x * 256 + threadIdx.x;
    if (idx >= (size_t)MPAD * D_) return;
    int d = (int)(idx % D_);
    int row = (int)(idx / D_);
    float v = 0.f;
    if (row < M_) {
        int b = row / S_, s = row % S_;
        if (s == 0) v = cls[d] + pos[d];
        else        v = pe[((size_t)b * NP_ + (s - 1)) * D_ + d] + pos[(size_t)s * D_ + d];
    }
    h[idx] = v;
}

__device__ __forceinline__ float block_reduce_sum(float val) {
    __shared__ float sm[4];
    #pragma unroll
    for (int off = 32; off > 0; off >>= 1) val += __shfl_xor(val, off, 64);
    int wid = threadIdx.x >> 6;
    if ((threadIdx.x & 63) == 0) sm[wid] = val;
    __syncthreads();
    float r = (sm[0] + sm[1]) + (sm[2] + sm[3]);
    __syncthreads();
    return r;
}

template<bool BF16OUT>
__global__ __launch_bounds__(256)
void ln_k(const float* __restrict__ x, size_t xstride,
          void* __restrict__ y, size_t ystride,
          const float* __restrict__ s, const float* __restrict__ b) {
    const float* xr = x + (size_t)blockIdx.x * xstride;
    const int tid = threadIdx.x;
    float v[3];
    float sum = 0.f;
    #pragma unroll
    for (int t = 0; t < 3; ++t) { v[t] = xr[tid + t * 256]; sum += v[t]; }
    sum = block_reduce_sum(sum);
    const float mu = sum * (1.0f / 768.0f);
    float vs = 0.f;
    #pragma unroll
    for (int t = 0; t < 3; ++t) { float d = v[t] - mu; vs += d * d; }
    vs = block_reduce_sum(vs);
    const float rstd = rsqrtf(vs * (1.0f / 768.0f) + 1e-6f);
    #pragma unroll
    for (int t = 0; t < 3; ++t) {
        int c = tid + t * 256;
        float r = (v[t] - mu) * rstd * s[c] + b[c];
        if (BF16OUT) ((ushort_t*)y)[(size_t)blockIdx.x * ystride + c] = f2bf(r);
        else         ((float*)y)[(size_t)blockIdx.x * ystride + c] = r;
    }
}

// ====================== launch ======================
extern "C" void kernel_launch(void* const* d_in, const int* in_sizes, int n_in,
                              void* d_out, int out_size, void* d_ws, size_t ws_size,
                              hipStream_t stream) {
    const float* x       = (const float*)d_in[0];
    const float* patch_w = (const float*)d_in[1];
    const float* patch_b = (const float*)d_in[2];
    const float* cls_tok = (const float*)d_in[3];
    const float* pos_emb = (const float*)d_in[4];
    const float* ln1_s   = (const float*)d_in[5];
    const float* ln1_b   = (const float*)d_in[6];
    const float* qw      = (const float*)d_in[7];
    const float* qb      = (const float*)d_in[8];
    const float* kw      = (const float*)d_in[9];
    const float* kb      = (const float*)d_in[10];
    const float* vw      = (const float*)d_in[11];
    const float* vb      = (const float*)d_in[12];
    const float* pw      = (const float*)d_in[13];
    const float* pb      = (const float*)d_in[14];
    const float* ln2_s   = (const float*)d_in[15];
    const float* ln2_b   = (const float*)d_in[16];
    const float* fc1_w   = (const float*)d_in[17];
    const float* fc1_b   = (const float*)d_in[18];
    const float* fc2_w   = (const float*)d_in[19];
    const float* fc2_b   = (const float*)d_in[20];
    const float* lnf_s   = (const float*)d_in[21];
    const float* lnf_b   = (const float*)d_in[22];
    float* out = (float*)d_out;

    // ---- workspace layout (bytes) ----
    char* ws = (char*)d_ws;
    float*    h      = (float*)ws;                                   // MPAD*768 f32
    ushort_t* yb     = (ushort_t*)(ws + 38928384);                   // MPAD*768 bf16
    char*     Ubase  = ws + 58392576;                                 // 77,856,768 B shared region
    ushort_t* qkvb   = (ushort_t*)Ubase;                              // MPAD*2304 bf16
    ushort_t* ub     = (ushort_t*)Ubase;                              // MPAD*3072 bf16
    float*    peb    = (float*)Ubase;                                 // MP_*768 f32 (prologue)
    ushort_t* wqkv_t = (ushort_t*)(ws + 136249344);                   // 12*2304*768
    ushort_t* wp_t   = (ushort_t*)(ws + 178716672);                   // 12*768*768
    ushort_t* w1_t   = (ushort_t*)(ws + 192872448);                   // 12*3072*768
    ushort_t* w2_t   = (ushort_t*)(ws + 249495552);                   // 12*768*3072
    ushort_t* pwt    = (ushort_t*)(ws + 306118656);                   // 768*768
    float*    bqkv   = (float*)(ws + 307298304);                      // 12*2304 f32

    const dim3 blk(256);

    // ---- weight prep ----
    tcast_k<<<dim3(768 / 32, 768 / 32, 12), blk, 0, stream>>>(qw, wqkv_t,            768, 768, (size_t)768 * 768, (size_t)2304 * 768);
    tcast_k<<<dim3(768 / 32, 768 / 32, 12), blk, 0, stream>>>(kw, wqkv_t + 768 * 768, 768, 768, (size_t)768 * 768, (size_t)2304 * 768);
    tcast_k<<<dim3(768 / 32, 768 / 32, 12), blk, 0, stream>>>(vw, wqkv_t + 1536 * 768, 768, 768, (size_t)768 * 768, (size_t)2304 * 768);
    tcast_k<<<dim3(768 / 32, 768 / 32, 12), blk, 0, stream>>>(pw, wp_t, 768, 768, (size_t)768 * 768, (size_t)768 * 768);
    tcast_k<<<dim3(3072 / 32, 768 / 32, 12), blk, 0, stream>>>(fc1_w, w1_t, 768, 3072, (size_t)768 * 3072, (size_t)3072 * 768);
    tcast_k<<<dim3(768 / 32, 3072 / 32, 12), blk, 0, stream>>>(fc2_w, w2_t, 3072, 768, (size_t)3072 * 768, (size_t)768 * 3072);
    cast_k<<<dim3((768 * 768 + 255) / 256), blk, 0, stream>>>(patch_w, pwt, 768 * 768);
    biascat_k<<<dim3((DEPTH_ * 2304 + 255) / 256), blk, 0, stream>>>(qb, kb, vb, bqkv);
    zeroyb_k<<<dim3(((MPAD - M_) * 768 + 255) / 256), blk, 0, stream>>>(yb);

    // ---- patch embed ----
    im2col_k<<<dim3(((size_t)MP_ * 768 + 255) / 256), blk, 0, stream>>>(x, yb);
    mm_k<3><<<dim3(768 / BN, MP_ / BM), blk, 0, stream>>>(yb, pwt, patch_b, nullptr, peb, MP_, 768, 768);
    assemble_k<<<dim3(((size_t)MPAD * D_ + 255) / 256), blk, 0, stream>>>(peb, cls_tok, pos_emb, h);

    // ---- transformer blocks ----
    const dim3 gQKV(2304 / BN, MPAD / BM);
    const dim3 gD(768 / BN, MPAD / BM);
    const dim3 gFF(FF_ / BN, MPAD / BM);
    for (int l = 0; l < DEPTH_; ++l) {
        const size_t oDD = (size_t)l * 768 * 768;
        const size_t oD  = (size_t)l * 768;
        const size_t oDF = (size_t)l * 768 * FF_;
        const size_t oF  = (size_t)l * FF_;

        ln_k<true><<<dim3(M_), blk, 0, stream>>>(h, 768, yb, 768, ln1_s + oD, ln1_b + oD);
        mm_k<0><<<gQKV, blk, 0, stream>>>(yb, wqkv_t + (size_t)l * 2304 * 768, bqkv + (size_t)l * 2304, nullptr, qkvb, MPAD, 2304, 768);
        attn2_k<<<dim3(H_, B_), blk, 0, stream>>>(qkvb, yb);
        mm_k<2><<<gD, blk, 0, stream>>>(yb, wp_t + oDD, pb + oD, h, h, MPAD, 768, 768);
        ln_k<true><<<dim3(M_), blk, 0, stream>>>(h, 768, yb, 768, ln2_s + oD, ln2_b + oD);
        mm_k<1><<<gFF, blk, 0, stream>>>(yb, w1_t + oDF, fc1_b + oF, nullptr, ub, MPAD, FF_, 768);
        mm_k<2><<<gD, blk, 0, stream>>>(ub, w2_t + oDF, fc2_b + oD, h, h, MPAD, 768, FF_);
    }

    // ---- final LN on CLS rows ----
    ln_k<false><<<dim3(B_), blk, 0, stream>>>(h, (size_t)S_ * D_, out, 768, lnf_s, lnf_b);
}